// Round 4
// baseline (1075.996 us; speedup 1.0000x reference)
//
#include <hip/hip_runtime.h>
#include <hip/hip_bf16.h>

// ---------------------------------------------------------------------------
// Gemma2 attention layer: qkv proj -> rope -> causal GQA attn (softcap) -> o proj
// T=2048 HID=3584 NH=16 NKV=8 HD=256
// R9: R8's register-pipelining spilled to scratch (WRITE_SIZE 16->484MB) and
// regressed; reverted to the R7 inner loop (fits 128 VGPR). Occupancy fix is
// now structural: one block per (head, 16-row q-chunk), 4 waves split the key
// range 4-ways (flash-decoding), merged by a once-per-block LDS tree combine.
// 2048 blocks -> 2x wave supply + dynamic load balance (heavy chunks first).
// GEMMs (m97 structure) and prep unchanged.
// ---------------------------------------------------------------------------

#define T_SEQ 2048
#define HID_DIM 3584
#define NH 16
#define NKV 8
#define HD 256
#define QKV_N ((NH + 2 * NKV) * HD)   // 8192
#define ATT_N (NH * HD)               // 4096
#define V_OFF ((NH + NKV) * HD)       // 6144

typedef __bf16 bf16_t;
typedef bf16_t bf16x8 __attribute__((ext_vector_type(8)));
typedef float f32x4 __attribute__((ext_vector_type(4)));

// async global->LDS, 16B per lane; LDS dest is wave-uniform base + lane*16
__device__ __forceinline__ void gload16(const bf16_t* g, bf16_t* l) {
  __builtin_amdgcn_global_load_lds(
      (const __attribute__((address_space(1))) unsigned int*)g,
      (__attribute__((address_space(3))) unsigned int*)l, 16, 0, 0);
}

// ---------------------------------------------------------------------------
// Prep 1: fp32 -> bf16 linear convert (hidden_states). n = grid*256*8 exactly.
// ---------------------------------------------------------------------------
__global__ __launch_bounds__(256) void convert_bf16(
    const float* __restrict__ in, bf16_t* __restrict__ out) {
  const long i = ((long)blockIdx.x * 256 + threadIdx.x) * 8;
  const float4 f0 = *(const float4*)(in + i);
  const float4 f1 = *(const float4*)(in + i + 4);
  bf16x8 v;
  v[0] = (bf16_t)f0.x; v[1] = (bf16_t)f0.y; v[2] = (bf16_t)f0.z; v[3] = (bf16_t)f0.w;
  v[4] = (bf16_t)f1.x; v[5] = (bf16_t)f1.y; v[6] = (bf16_t)f1.z; v[7] = (bf16_t)f1.w;
  *(bf16x8*)(out + i) = v;
}

// ---------------------------------------------------------------------------
// Prep 2: transpose + convert: in [K,N] fp32 -> out [N,K] bf16. 64x64 tiles,
// coalesced reads (float4) and writes (bf16x8) via LDS.
// ---------------------------------------------------------------------------
__global__ __launch_bounds__(256) void transpose_bf16(
    const float* __restrict__ in, bf16_t* __restrict__ out, int K, int N) {
  __shared__ __align__(16) bf16_t tile[64][80];  // [n][k], 160B rows (16B-aligned)
  const int k0 = blockIdx.x * 64;
  const int n0 = blockIdx.y * 64;
  const int t = threadIdx.x;
  const int rr = t >> 4;          // 0..15 (k within pass)
  const int rc = (t & 15) * 4;    // n offset
#pragma unroll
  for (int i = 0; i < 4; ++i) {
    const int k = rr + i * 16;
    const float4 v = *(const float4*)(in + (long)(k0 + k) * N + n0 + rc);
    tile[rc + 0][k] = (bf16_t)v.x;
    tile[rc + 1][k] = (bf16_t)v.y;
    tile[rc + 2][k] = (bf16_t)v.z;
    tile[rc + 3][k] = (bf16_t)v.w;
  }
  __syncthreads();
  const int wn = t >> 3;          // 0..31
  const int wk = (t & 7) * 8;     // 0..56
#pragma unroll
  for (int i = 0; i < 2; ++i) {
    const int n = wn + i * 32;
    *(bf16x8*)(out + (long)(n0 + n) * K + k0 + wk) = *(const bf16x8*)&tile[n][wk];
  }
}

// ---------------------------------------------------------------------------
// GEMM (m97 structure): C[M,N] = A[M,K] @ Bt[N,K]^T, both bf16 row-major.
// Block 256 (4 waves), tile 128x128, BK=32. Columns >= voff are written
// TRANSPOSED to Vt[(col-voff)*QKV_N + row].
// ---------------------------------------------------------------------------
template <typename TC>
__global__ __launch_bounds__(256) void gemm_bt(
    const bf16_t* __restrict__ A, const bf16_t* __restrict__ Bt,
    TC* __restrict__ C, bf16_t* __restrict__ Vt, int voff,
    int M, int N, int K) {
  const int n0 = blockIdx.x * 128;
  const int m0 = blockIdx.y * 128;
  const int t = threadIdx.x;
  const int w = t >> 6;
  const int lane = t & 63;
  const int l16 = lane & 15;
  const int quad = lane >> 4;

  __shared__ __align__(16) bf16_t As[128][32];  // 8KB
  __shared__ __align__(16) bf16_t Bs[128][32];  // 8KB

  f32x4 acc[4][4];
#pragma unroll
  for (int i = 0; i < 4; ++i)
#pragma unroll
    for (int j = 0; j < 4; ++j) acc[i][j] = f32x4{0, 0, 0, 0};

  const int srow = lane >> 2;        // row within 16-row unit
  const int scol = (lane & 3) * 8;   // elem col within BK=32
  const bf16_t* gsrc;
  bf16_t* lbase;
  if (w < 2) {
    gsrc = A + (long)(m0 + w * 64 + srow) * K + scol;
    lbase = &As[w * 64][0];
  } else {
    gsrc = Bt + (long)(n0 + (w - 2) * 64 + srow) * K + scol;
    lbase = &Bs[(w - 2) * 64][0];
  }

  const int wm = w & 1;
  const int wn = w >> 1;

  for (int k0 = 0; k0 < K; k0 += 32) {
#pragma unroll
    for (int j = 0; j < 4; ++j)
      gload16(gsrc + (long)j * 16 * K + k0, lbase + j * (16 * 32));
    __syncthreads();

    bf16x8 af[4], bfr[4];
#pragma unroll
    for (int i = 0; i < 4; ++i) {
      af[i] = *(const bf16x8*)&As[wm * 64 + i * 16 + l16][quad * 8];
      bfr[i] = *(const bf16x8*)&Bs[wn * 64 + i * 16 + l16][quad * 8];
    }
#pragma unroll
    for (int i = 0; i < 4; ++i)
#pragma unroll
      for (int j = 0; j < 4; ++j)
        acc[i][j] = __builtin_amdgcn_mfma_f32_16x16x32_bf16(af[i], bfr[j],
                                                            acc[i][j], 0, 0, 0);
    __syncthreads();
  }

#pragma unroll
  for (int i = 0; i < 4; ++i) {
    const int row = m0 + wm * 64 + i * 16 + quad * 4;
#pragma unroll
    for (int j = 0; j < 4; ++j) {
      const int col = n0 + wn * 64 + j * 16 + l16;
#pragma unroll
      for (int r = 0; r < 4; ++r) {
        if (col >= voff)
          Vt[(long)(col - voff) * QKV_N + (row + r)] = (bf16_t)acc[i][j][r];
        else
          C[(long)(row + r) * N + col] = (TC)acc[i][j][r];
      }
    }
  }
}

// ---------------------------------------------------------------------------
// Neox-style RoPE over full HD=256, in-place on bf16 qkv (q: 16 heads, k: 8).
// ---------------------------------------------------------------------------
__global__ void rope_kernel(const int* __restrict__ positions,
                            bf16_t* __restrict__ qkv) {
  const int head = blockIdx.x;   // 0..23 : 0..15 q heads, 16..23 k heads
  const int trow = blockIdx.y;
  const int d = threadIdx.x;     // 0..127 (pairs with d+128)
  const long col0 = (head < NH) ? (long)head * HD
                                : (long)(NH * HD) + (long)(head - NH) * HD;
  bf16_t* p = qkv + (long)trow * QKV_N + col0;
  const float pos = (float)positions[trow];
  const float inv_freq = exp2f(-(float)d * (13.287712379549449f / 128.0f));
  const float ang = pos * inv_freq;
  float s, c;
  sincosf(ang, &s, &c);
  const float x1 = (float)p[d];
  const float x2 = (float)p[d + 128];
  p[d]       = (bf16_t)(x1 * c - x2 * s);
  p[d + 128] = (bf16_t)(x2 * c + x1 * s);
}

// ---------------------------------------------------------------------------
// R9 flash attention: one block per (head, 16-row q-chunk); 4 waves split the
// key-tile range 4-ways (flash-decoding). Each wave runs the R7 inner loop
// (128-VGPR-resident, barrier-free) over its quarter with private (m,l,O);
// a once-per-block LDS tree combine merges the 4 partials.
// Grid = 2048 blocks, heavy chunks first; kvh pinned to XCD (lid&7).
// ---------------------------------------------------------------------------
__global__ __launch_bounds__(256, 4) void attn_mfma(
    const bf16_t* __restrict__ qkv, const bf16_t* __restrict__ vt,
    bf16_t* __restrict__ out /* [T, 4096] */) {
  const int lid = blockIdx.x;            // 0..2047
  const int kvh = lid & 7;               // XCD-pinned KV head
  const int slot = lid >> 3;             // 0..255
  const int h = 2 * kvh + (slot & 1);
  const int chunk = 127 - (slot >> 1);   // heavy chunks dispatched first
  const int q0 = chunk * 16;
  const int ktiles = (chunk >> 1) + 1;   // 32-key tiles covering keys<=q0+15
  const int t = threadIdx.x;
  const int w = t >> 6;
  const int lane = t & 63;
  const int l16 = lane & 15;
  const int quad = lane >> 4;
  // 4-way key split across waves
  const int base = ktiles >> 2;
  const int rem = ktiles & 3;
  const int cnt = base + (w < rem ? 1 : 0);
  const int start = w * base + (w < rem ? w : rem);

  __shared__ __align__(16) bf16_t Ps[4][16][40];  // per-wave P slab (5KB)
  __shared__ float sm[4][16], sl[4][16];
  __shared__ __align__(16) float slabA[16][260];  // padded: 2-way banks only
  __shared__ __align__(16) float slabB[16][260];

  // Q A-frags: A[m=l16][k=quad*8+j], d in 8 steps of 32 (same rows all waves)
  bf16x8 qf[8];
  const bf16_t* qbase = qkv + (long)(q0 + l16) * QKV_N + h * HD + quad * 8;
#pragma unroll
  for (int s = 0; s < 8; ++s) qf[s] = *(const bf16x8*)(qbase + s * 32);

  const bf16_t* kbase = qkv + (long)l16 * QKV_N + (NH * HD) + kvh * HD + quad * 8;
  const bf16_t* vbase = vt + (long)(kvh * HD + l16) * QKV_N + quad * 8;

  f32x4 oacc[16];  // O[16q][256d]: frag nt -> cols nt*16+l16
#pragma unroll
  for (int nt = 0; nt < 16; ++nt) oacc[nt] = f32x4{0, 0, 0, 0};
  float m_state[4], l_state[4];
#pragma unroll
  for (int r = 0; r < 4; ++r) { m_state[r] = -1e30f; l_state[r] = 0.0f; }

  for (int kt = start; kt < start + cnt; ++kt) {
    // K B-frags: B[n=key16][k=d], 2 key-groups x 8 d-steps
    bf16x8 kf[2][8];
    const bf16_t* kp = kbase + (long)(kt * 32) * QKV_N;
#pragma unroll
    for (int g = 0; g < 2; ++g)
#pragma unroll
      for (int s = 0; s < 8; ++s)
        kf[g][s] = *(const bf16x8*)(kp + (long)(g * 16) * QKV_N + s * 32);

    f32x4 sacc[2] = {f32x4{0, 0, 0, 0}, f32x4{0, 0, 0, 0}};
    __builtin_amdgcn_s_setprio(1);
#pragma unroll
    for (int g = 0; g < 2; ++g)
#pragma unroll
      for (int s = 0; s < 8; ++s)
        sacc[g] = __builtin_amdgcn_mfma_f32_16x16x32_bf16(qf[s], kf[g][s],
                                                          sacc[g], 0, 0, 0);
    __builtin_amdgcn_s_setprio(0);

    // softcap + causal + wave-internal online softmax
    float alpha[4];
#pragma unroll
    for (int r = 0; r < 4; ++r) {
      const int row = q0 + quad * 4 + r;
      float svg[2];
      float best = -1e30f;
#pragma unroll
      for (int g = 0; g < 2; ++g) {
        const float x = sacc[g][r] * 0.0625f;
        const float e = __expf(x * 0.04f);           // e^(2x/50)
        const float tz = 50.0f * (e - 1.0f) / (e + 1.0f);
        const int col = kt * 32 + g * 16 + l16;
        svg[g] = (col <= row) ? tz : -1e30f;
        best = fmaxf(best, svg[g]);
      }
      best = fmaxf(best, __shfl_xor(best, 1));
      best = fmaxf(best, __shfl_xor(best, 2));
      best = fmaxf(best, __shfl_xor(best, 4));
      best = fmaxf(best, __shfl_xor(best, 8));
      const float mnew = fmaxf(m_state[r], best);
      float psum = 0.0f;
#pragma unroll
      for (int g = 0; g < 2; ++g) {
        const float pv = (svg[g] > -1e29f) ? __expf(svg[g] - mnew) : 0.0f;
        Ps[w][quad * 4 + r][g * 16 + l16] = (bf16_t)pv;
        psum += pv;
      }
      psum += __shfl_xor(psum, 1);
      psum += __shfl_xor(psum, 2);
      psum += __shfl_xor(psum, 4);
      psum += __shfl_xor(psum, 8);
      alpha[r] = __expf(m_state[r] - mnew);
      l_state[r] = l_state[r] * alpha[r] + psum;
      m_state[r] = mnew;
    }
#pragma unroll
    for (int nt = 0; nt < 16; ++nt) {
      oacc[nt][0] *= alpha[0];
      oacc[nt][1] *= alpha[1];
      oacc[nt][2] *= alpha[2];
      oacc[nt][3] *= alpha[3];
    }

    // wave-internal transpose: C-layout write above, A-layout read here
    const bf16x8 pa = *(const bf16x8*)&Ps[w][l16][quad * 8];

    // PV in two d-halves to cap VGPR: B[n=d][k=key] frags from V^T
#pragma unroll
    for (int h2 = 0; h2 < 2; ++h2) {
      bf16x8 vf[8];
#pragma unroll
      for (int nt = 0; nt < 8; ++nt)
        vf[nt] = *(const bf16x8*)(vbase + (long)(h2 * 128 + nt * 16) * QKV_N +
                                  kt * 32);
      __builtin_amdgcn_s_setprio(1);
#pragma unroll
      for (int nt = 0; nt < 8; ++nt)
        oacc[h2 * 8 + nt] = __builtin_amdgcn_mfma_f32_16x16x32_bf16(
            pa, vf[nt], oacc[h2 * 8 + nt], 0, 0, 0);
      __builtin_amdgcn_s_setprio(0);
    }
  }

  // ---- once-per-block combine of the 4 wave partials -----------------------
  if (l16 == 0) {
#pragma unroll
    for (int r = 0; r < 4; ++r) {
      sm[w][quad * 4 + r] = m_state[r];
      sl[w][quad * 4 + r] = l_state[r];
    }
  }
  __syncthreads();

  float fac[4], lsum[4];
#pragma unroll
  for (int r = 0; r < 4; ++r) {
    const int row = quad * 4 + r;
    const float mstar = fmaxf(fmaxf(sm[0][row], sm[1][row]),
                              fmaxf(sm[2][row], sm[3][row]));
    fac[r] = __expf(m_state[r] - mstar);
    float ls = 0.0f;
#pragma unroll
    for (int j = 0; j < 4; ++j) ls += __expf(sm[j][row] - mstar) * sl[j][row];
    lsum[r] = ls;
  }
#pragma unroll
  for (int nt = 0; nt < 16; ++nt) {
    oacc[nt][0] *= fac[0];
    oacc[nt][1] *= fac[1];
    oacc[nt][2] *= fac[2];
    oacc[nt][3] *= fac[3];
  }

  // tree reduce: (1 -> A, 3 -> B) ; (0 += A, 2 += B) ; (2 -> A) ; (0 += A)
  if (w == 1 || w == 3) {
    float(*slab)[260] = (w == 1) ? slabA : slabB;
#pragma unroll
    for (int r = 0; r < 4; ++r)
#pragma unroll
      for (int nt = 0; nt < 16; ++nt)
        slab[quad * 4 + r][nt * 16 + l16] = oacc[nt][r];
  }
  __syncthreads();
  if (w == 0) {
#pragma unroll
    for (int r = 0; r < 4; ++r)
#pragma unroll
      for (int nt = 0; nt < 16; ++nt)
        oacc[nt][r] += slabA[quad * 4 + r][nt * 16 + l16];
  } else if (w == 2) {
#pragma unroll
    for (int r = 0; r < 4; ++r)
#pragma unroll
      for (int nt = 0; nt < 16; ++nt)
        oacc[nt][r] += slabB[quad * 4 + r][nt * 16 + l16];
  }
  __syncthreads();
  if (w == 2) {
#pragma unroll
    for (int r = 0; r < 4; ++r)
#pragma unroll
      for (int nt = 0; nt < 16; ++nt)
        slabA[quad * 4 + r][nt * 16 + l16] = oacc[nt][r];
  }
  __syncthreads();
  if (w == 0) {
#pragma unroll
    for (int r = 0; r < 4; ++r) {
      const float inv = 1.0f / lsum[r];
      bf16_t* op = out + (long)(q0 + quad * 4 + r) * ATT_N + h * HD + l16;
#pragma unroll
      for (int nt = 0; nt < 16; ++nt)
        op[nt * 16] =
            (bf16_t)((oacc[nt][r] + slabA[quad * 4 + r][nt * 16 + l16]) * inv);
    }
  }
}

// ---------------------------------------------------------------------------
extern "C" void kernel_launch(void* const* d_in, const int* in_sizes, int n_in,
                              void* d_out, int out_size, void* d_ws, size_t ws_size,
                              hipStream_t stream) {
  const int* positions = (const int*)d_in[0];
  const float* hidden = (const float*)d_in[1];
  const float* w_qkv = (const float*)d_in[2];
  const float* w_o = (const float*)d_in[3];
  float* out = (float*)d_out;

  // workspace layout (bf16): total ~153 MB
  bf16_t* qkv = (bf16_t*)d_ws;                          // [2048, 8192]  33.6MB
  bf16_t* attn = qkv + (size_t)T_SEQ * QKV_N;           // [2048, 4096]  16.8MB
  bf16_t* hid_bf = attn + (size_t)T_SEQ * ATT_N;        // [2048, 3584]  14.7MB
  bf16_t* wqkv_t = hid_bf + (size_t)T_SEQ * HID_DIM;    // [8192, 3584]  58.7MB
  bf16_t* wo_t = wqkv_t + (size_t)QKV_N * HID_DIM;      // [3584, 4096]  29.4MB
  bf16_t* vtb = qkv + V_OFF;  // V^T lives in the V slot: vt(d,t)=vtb[d*8192+t]

  // 0) prep: bf16 convert + weight transposes
  convert_bf16<<<(T_SEQ * HID_DIM) / 2048, 256, 0, stream>>>(hidden, hid_bf);
  transpose_bf16<<<dim3(HID_DIM / 64, QKV_N / 64), 256, 0, stream>>>(
      w_qkv, wqkv_t, HID_DIM, QKV_N);
  transpose_bf16<<<dim3(ATT_N / 64, HID_DIM / 64), 256, 0, stream>>>(
      w_o, wo_t, ATT_N, HID_DIM);

  // 1) qkv = hidden @ w_qkv ; V columns routed transposed into vtb
  gemm_bt<bf16_t><<<dim3(QKV_N / 128, T_SEQ / 128), 256, 0, stream>>>(
      hid_bf, wqkv_t, qkv, vtb, V_OFF, T_SEQ, QKV_N, HID_DIM);
  // 2) rope on q,k in-place (V slot untouched)
  rope_kernel<<<dim3(NH + NKV, T_SEQ), 128, 0, stream>>>(positions, qkv);
  // 3) flash-decoding MFMA attention (2048 blocks, 4-way K split per block)
  attn_mfma<<<2048, 256, 0, stream>>>(qkv, vtb, attn);
  // 4) out = attn @ w_o
  gemm_bt<float><<<dim3(HID_DIM / 128, T_SEQ / 128), 256, 0, stream>>>(
      attn, wo_t, out, attn /*unused*/, 1 << 30, T_SEQ, HID_DIM, ATT_N);
}

// Round 5
// 843.449 us; speedup vs baseline: 1.2757x; 1.2757x over previous
//
#include <hip/hip_runtime.h>
#include <hip/hip_bf16.h>

// ---------------------------------------------------------------------------
// Gemma2 attention layer: qkv proj -> rope -> causal GQA attn (softcap) -> o proj
// T=2048 HID=3584 NH=16 NKV=8 HD=256
// R10: R9's flash-decoding structure with the launch-bounds clamp REMOVED.
// R9's __launch_bounds__(256,4) capped VGPR at 64 -> 1.39GB scratch spill
// (oacc lived in memory). Plain __launch_bounds__(256) restores R7's proven
// 128-VGPR allocation; the 2048-block grid + 4-way key split now actually
// delivers 16 resident waves/CU. GEMMs (m97 structure) and prep unchanged.
// ---------------------------------------------------------------------------

#define T_SEQ 2048
#define HID_DIM 3584
#define NH 16
#define NKV 8
#define HD 256
#define QKV_N ((NH + 2 * NKV) * HD)   // 8192
#define ATT_N (NH * HD)               // 4096
#define V_OFF ((NH + NKV) * HD)       // 6144

typedef __bf16 bf16_t;
typedef bf16_t bf16x8 __attribute__((ext_vector_type(8)));
typedef float f32x4 __attribute__((ext_vector_type(4)));

// async global->LDS, 16B per lane; LDS dest is wave-uniform base + lane*16
__device__ __forceinline__ void gload16(const bf16_t* g, bf16_t* l) {
  __builtin_amdgcn_global_load_lds(
      (const __attribute__((address_space(1))) unsigned int*)g,
      (__attribute__((address_space(3))) unsigned int*)l, 16, 0, 0);
}

// ---------------------------------------------------------------------------
// Prep 1: fp32 -> bf16 linear convert (hidden_states). n = grid*256*8 exactly.
// ---------------------------------------------------------------------------
__global__ __launch_bounds__(256) void convert_bf16(
    const float* __restrict__ in, bf16_t* __restrict__ out) {
  const long i = ((long)blockIdx.x * 256 + threadIdx.x) * 8;
  const float4 f0 = *(const float4*)(in + i);
  const float4 f1 = *(const float4*)(in + i + 4);
  bf16x8 v;
  v[0] = (bf16_t)f0.x; v[1] = (bf16_t)f0.y; v[2] = (bf16_t)f0.z; v[3] = (bf16_t)f0.w;
  v[4] = (bf16_t)f1.x; v[5] = (bf16_t)f1.y; v[6] = (bf16_t)f1.z; v[7] = (bf16_t)f1.w;
  *(bf16x8*)(out + i) = v;
}

// ---------------------------------------------------------------------------
// Prep 2: transpose + convert: in [K,N] fp32 -> out [N,K] bf16. 64x64 tiles,
// coalesced reads (float4) and writes (bf16x8) via LDS.
// ---------------------------------------------------------------------------
__global__ __launch_bounds__(256) void transpose_bf16(
    const float* __restrict__ in, bf16_t* __restrict__ out, int K, int N) {
  __shared__ __align__(16) bf16_t tile[64][80];  // [n][k], 160B rows (16B-aligned)
  const int k0 = blockIdx.x * 64;
  const int n0 = blockIdx.y * 64;
  const int t = threadIdx.x;
  const int rr = t >> 4;          // 0..15 (k within pass)
  const int rc = (t & 15) * 4;    // n offset
#pragma unroll
  for (int i = 0; i < 4; ++i) {
    const int k = rr + i * 16;
    const float4 v = *(const float4*)(in + (long)(k0 + k) * N + n0 + rc);
    tile[rc + 0][k] = (bf16_t)v.x;
    tile[rc + 1][k] = (bf16_t)v.y;
    tile[rc + 2][k] = (bf16_t)v.z;
    tile[rc + 3][k] = (bf16_t)v.w;
  }
  __syncthreads();
  const int wn = t >> 3;          // 0..31
  const int wk = (t & 7) * 8;     // 0..56
#pragma unroll
  for (int i = 0; i < 2; ++i) {
    const int n = wn + i * 32;
    *(bf16x8*)(out + (long)(n0 + n) * K + k0 + wk) = *(const bf16x8*)&tile[n][wk];
  }
}

// ---------------------------------------------------------------------------
// GEMM (m97 structure): C[M,N] = A[M,K] @ Bt[N,K]^T, both bf16 row-major.
// Block 256 (4 waves), tile 128x128, BK=32. Columns >= voff are written
// TRANSPOSED to Vt[(col-voff)*QKV_N + row].
// ---------------------------------------------------------------------------
template <typename TC>
__global__ __launch_bounds__(256) void gemm_bt(
    const bf16_t* __restrict__ A, const bf16_t* __restrict__ Bt,
    TC* __restrict__ C, bf16_t* __restrict__ Vt, int voff,
    int M, int N, int K) {
  const int n0 = blockIdx.x * 128;
  const int m0 = blockIdx.y * 128;
  const int t = threadIdx.x;
  const int w = t >> 6;
  const int lane = t & 63;
  const int l16 = lane & 15;
  const int quad = lane >> 4;

  __shared__ __align__(16) bf16_t As[128][32];  // 8KB
  __shared__ __align__(16) bf16_t Bs[128][32];  // 8KB

  f32x4 acc[4][4];
#pragma unroll
  for (int i = 0; i < 4; ++i)
#pragma unroll
    for (int j = 0; j < 4; ++j) acc[i][j] = f32x4{0, 0, 0, 0};

  const int srow = lane >> 2;        // row within 16-row unit
  const int scol = (lane & 3) * 8;   // elem col within BK=32
  const bf16_t* gsrc;
  bf16_t* lbase;
  if (w < 2) {
    gsrc = A + (long)(m0 + w * 64 + srow) * K + scol;
    lbase = &As[w * 64][0];
  } else {
    gsrc = Bt + (long)(n0 + (w - 2) * 64 + srow) * K + scol;
    lbase = &Bs[(w - 2) * 64][0];
  }

  const int wm = w & 1;
  const int wn = w >> 1;

  for (int k0 = 0; k0 < K; k0 += 32) {
#pragma unroll
    for (int j = 0; j < 4; ++j)
      gload16(gsrc + (long)j * 16 * K + k0, lbase + j * (16 * 32));
    __syncthreads();

    bf16x8 af[4], bfr[4];
#pragma unroll
    for (int i = 0; i < 4; ++i) {
      af[i] = *(const bf16x8*)&As[wm * 64 + i * 16 + l16][quad * 8];
      bfr[i] = *(const bf16x8*)&Bs[wn * 64 + i * 16 + l16][quad * 8];
    }
#pragma unroll
    for (int i = 0; i < 4; ++i)
#pragma unroll
      for (int j = 0; j < 4; ++j)
        acc[i][j] = __builtin_amdgcn_mfma_f32_16x16x32_bf16(af[i], bfr[j],
                                                            acc[i][j], 0, 0, 0);
    __syncthreads();
  }

#pragma unroll
  for (int i = 0; i < 4; ++i) {
    const int row = m0 + wm * 64 + i * 16 + quad * 4;
#pragma unroll
    for (int j = 0; j < 4; ++j) {
      const int col = n0 + wn * 64 + j * 16 + l16;
#pragma unroll
      for (int r = 0; r < 4; ++r) {
        if (col >= voff)
          Vt[(long)(col - voff) * QKV_N + (row + r)] = (bf16_t)acc[i][j][r];
        else
          C[(long)(row + r) * N + col] = (TC)acc[i][j][r];
      }
    }
  }
}

// ---------------------------------------------------------------------------
// Neox-style RoPE over full HD=256, in-place on bf16 qkv (q: 16 heads, k: 8).
// ---------------------------------------------------------------------------
__global__ void rope_kernel(const int* __restrict__ positions,
                            bf16_t* __restrict__ qkv) {
  const int head = blockIdx.x;   // 0..23 : 0..15 q heads, 16..23 k heads
  const int trow = blockIdx.y;
  const int d = threadIdx.x;     // 0..127 (pairs with d+128)
  const long col0 = (head < NH) ? (long)head * HD
                                : (long)(NH * HD) + (long)(head - NH) * HD;
  bf16_t* p = qkv + (long)trow * QKV_N + col0;
  const float pos = (float)positions[trow];
  const float inv_freq = exp2f(-(float)d * (13.287712379549449f / 128.0f));
  const float ang = pos * inv_freq;
  float s, c;
  sincosf(ang, &s, &c);
  const float x1 = (float)p[d];
  const float x2 = (float)p[d + 128];
  p[d]       = (bf16_t)(x1 * c - x2 * s);
  p[d + 128] = (bf16_t)(x2 * c + x1 * s);
}

// ---------------------------------------------------------------------------
// R10 flash attention: one block per (head, 16-row q-chunk); 4 waves split the
// key-tile range 4-ways (flash-decoding). Each wave runs the R7 inner loop
// (128-VGPR-resident, barrier-free) over its quarter with private (m,l,O);
// a once-per-block LDS tree combine merges the 4 partials.
// Grid = 2048 blocks, heavy chunks first; kvh pinned to XCD (lid&7).
// NOTE: plain __launch_bounds__(256) — do NOT add a min-waves clamp; at
// min=4 the 64-VGPR cap spills oacc to scratch (R9: 1.39GB/dispatch).
// ---------------------------------------------------------------------------
__global__ __launch_bounds__(256) void attn_mfma(
    const bf16_t* __restrict__ qkv, const bf16_t* __restrict__ vt,
    bf16_t* __restrict__ out /* [T, 4096] */) {
  const int lid = blockIdx.x;            // 0..2047
  const int kvh = lid & 7;               // XCD-pinned KV head
  const int slot = lid >> 3;             // 0..255
  const int h = 2 * kvh + (slot & 1);
  const int chunk = 127 - (slot >> 1);   // heavy chunks dispatched first
  const int q0 = chunk * 16;
  const int ktiles = (chunk >> 1) + 1;   // 32-key tiles covering keys<=q0+15
  const int t = threadIdx.x;
  const int w = t >> 6;
  const int lane = t & 63;
  const int l16 = lane & 15;
  const int quad = lane >> 4;
  // 4-way key split across waves
  const int base = ktiles >> 2;
  const int rem = ktiles & 3;
  const int cnt = base + (w < rem ? 1 : 0);
  const int start = w * base + (w < rem ? w : rem);

  __shared__ __align__(16) bf16_t Ps[4][16][40];  // per-wave P slab (5KB)
  __shared__ float sm[4][16], sl[4][16];
  __shared__ __align__(16) float slabA[16][260];  // padded: 2-way banks only
  __shared__ __align__(16) float slabB[16][260];

  // Q A-frags: A[m=l16][k=quad*8+j], d in 8 steps of 32 (same rows all waves)
  bf16x8 qf[8];
  const bf16_t* qbase = qkv + (long)(q0 + l16) * QKV_N + h * HD + quad * 8;
#pragma unroll
  for (int s = 0; s < 8; ++s) qf[s] = *(const bf16x8*)(qbase + s * 32);

  const bf16_t* kbase = qkv + (long)l16 * QKV_N + (NH * HD) + kvh * HD + quad * 8;
  const bf16_t* vbase = vt + (long)(kvh * HD + l16) * QKV_N + quad * 8;

  f32x4 oacc[16];  // O[16q][256d]: frag nt -> cols nt*16+l16
#pragma unroll
  for (int nt = 0; nt < 16; ++nt) oacc[nt] = f32x4{0, 0, 0, 0};
  float m_state[4], l_state[4];
#pragma unroll
  for (int r = 0; r < 4; ++r) { m_state[r] = -1e30f; l_state[r] = 0.0f; }

  for (int kt = start; kt < start + cnt; ++kt) {
    // K B-frags: B[n=key16][k=d], 2 key-groups x 8 d-steps
    bf16x8 kf[2][8];
    const bf16_t* kp = kbase + (long)(kt * 32) * QKV_N;
#pragma unroll
    for (int g = 0; g < 2; ++g)
#pragma unroll
      for (int s = 0; s < 8; ++s)
        kf[g][s] = *(const bf16x8*)(kp + (long)(g * 16) * QKV_N + s * 32);

    f32x4 sacc[2] = {f32x4{0, 0, 0, 0}, f32x4{0, 0, 0, 0}};
    __builtin_amdgcn_s_setprio(1);
#pragma unroll
    for (int g = 0; g < 2; ++g)
#pragma unroll
      for (int s = 0; s < 8; ++s)
        sacc[g] = __builtin_amdgcn_mfma_f32_16x16x32_bf16(qf[s], kf[g][s],
                                                          sacc[g], 0, 0, 0);
    __builtin_amdgcn_s_setprio(0);

    // softcap + causal + wave-internal online softmax
    float alpha[4];
#pragma unroll
    for (int r = 0; r < 4; ++r) {
      const int row = q0 + quad * 4 + r;
      float svg[2];
      float best = -1e30f;
#pragma unroll
      for (int g = 0; g < 2; ++g) {
        const float x = sacc[g][r] * 0.0625f;
        const float e = __expf(x * 0.04f);           // e^(2x/50)
        const float tz = 50.0f * (e - 1.0f) / (e + 1.0f);
        const int col = kt * 32 + g * 16 + l16;
        svg[g] = (col <= row) ? tz : -1e30f;
        best = fmaxf(best, svg[g]);
      }
      best = fmaxf(best, __shfl_xor(best, 1));
      best = fmaxf(best, __shfl_xor(best, 2));
      best = fmaxf(best, __shfl_xor(best, 4));
      best = fmaxf(best, __shfl_xor(best, 8));
      const float mnew = fmaxf(m_state[r], best);
      float psum = 0.0f;
#pragma unroll
      for (int g = 0; g < 2; ++g) {
        const float pv = (svg[g] > -1e29f) ? __expf(svg[g] - mnew) : 0.0f;
        Ps[w][quad * 4 + r][g * 16 + l16] = (bf16_t)pv;
        psum += pv;
      }
      psum += __shfl_xor(psum, 1);
      psum += __shfl_xor(psum, 2);
      psum += __shfl_xor(psum, 4);
      psum += __shfl_xor(psum, 8);
      alpha[r] = __expf(m_state[r] - mnew);
      l_state[r] = l_state[r] * alpha[r] + psum;
      m_state[r] = mnew;
    }
#pragma unroll
    for (int nt = 0; nt < 16; ++nt) {
      oacc[nt][0] *= alpha[0];
      oacc[nt][1] *= alpha[1];
      oacc[nt][2] *= alpha[2];
      oacc[nt][3] *= alpha[3];
    }

    // wave-internal transpose: C-layout write above, A-layout read here
    const bf16x8 pa = *(const bf16x8*)&Ps[w][l16][quad * 8];

    // PV in two d-halves to cap VGPR: B[n=d][k=key] frags from V^T
#pragma unroll
    for (int h2 = 0; h2 < 2; ++h2) {
      bf16x8 vf[8];
#pragma unroll
      for (int nt = 0; nt < 8; ++nt)
        vf[nt] = *(const bf16x8*)(vbase + (long)(h2 * 128 + nt * 16) * QKV_N +
                                  kt * 32);
      __builtin_amdgcn_s_setprio(1);
#pragma unroll
      for (int nt = 0; nt < 8; ++nt)
        oacc[h2 * 8 + nt] = __builtin_amdgcn_mfma_f32_16x16x32_bf16(
            pa, vf[nt], oacc[h2 * 8 + nt], 0, 0, 0);
      __builtin_amdgcn_s_setprio(0);
    }
  }

  // ---- once-per-block combine of the 4 wave partials -----------------------
  if (l16 == 0) {
#pragma unroll
    for (int r = 0; r < 4; ++r) {
      sm[w][quad * 4 + r] = m_state[r];
      sl[w][quad * 4 + r] = l_state[r];
    }
  }
  __syncthreads();

  float fac[4], lsum[4];
#pragma unroll
  for (int r = 0; r < 4; ++r) {
    const int row = quad * 4 + r;
    const float mstar = fmaxf(fmaxf(sm[0][row], sm[1][row]),
                              fmaxf(sm[2][row], sm[3][row]));
    fac[r] = __expf(m_state[r] - mstar);
    float ls = 0.0f;
#pragma unroll
    for (int j = 0; j < 4; ++j) ls += __expf(sm[j][row] - mstar) * sl[j][row];
    lsum[r] = ls;
  }
#pragma unroll
  for (int nt = 0; nt < 16; ++nt) {
    oacc[nt][0] *= fac[0];
    oacc[nt][1] *= fac[1];
    oacc[nt][2] *= fac[2];
    oacc[nt][3] *= fac[3];
  }

  // tree reduce: (1 -> A, 3 -> B) ; (0 += A, 2 += B) ; (2 -> A) ; (0 += A)
  if (w == 1 || w == 3) {
    float(*slab)[260] = (w == 1) ? slabA : slabB;
#pragma unroll
    for (int r = 0; r < 4; ++r)
#pragma unroll
      for (int nt = 0; nt < 16; ++nt)
        slab[quad * 4 + r][nt * 16 + l16] = oacc[nt][r];
  }
  __syncthreads();
  if (w == 0) {
#pragma unroll
    for (int r = 0; r < 4; ++r)
#pragma unroll
      for (int nt = 0; nt < 16; ++nt)
        oacc[nt][r] += slabA[quad * 4 + r][nt * 16 + l16];
  } else if (w == 2) {
#pragma unroll
    for (int r = 0; r < 4; ++r)
#pragma unroll
      for (int nt = 0; nt < 16; ++nt)
        oacc[nt][r] += slabB[quad * 4 + r][nt * 16 + l16];
  }
  __syncthreads();
  if (w == 2) {
#pragma unroll
    for (int r = 0; r < 4; ++r)
#pragma unroll
      for (int nt = 0; nt < 16; ++nt)
        slabA[quad * 4 + r][nt * 16 + l16] = oacc[nt][r];
  }
  __syncthreads();
  if (w == 0) {
#pragma unroll
    for (int r = 0; r < 4; ++r) {
      const float inv = 1.0f / lsum[r];
      bf16_t* op = out + (long)(q0 + quad * 4 + r) * ATT_N + h * HD + l16;
#pragma unroll
      for (int nt = 0; nt < 16; ++nt)
        op[nt * 16] =
            (bf16_t)((oacc[nt][r] + slabA[quad * 4 + r][nt * 16 + l16]) * inv);
    }
  }
}

// ---------------------------------------------------------------------------
extern "C" void kernel_launch(void* const* d_in, const int* in_sizes, int n_in,
                              void* d_out, int out_size, void* d_ws, size_t ws_size,
                              hipStream_t stream) {
  const int* positions = (const int*)d_in[0];
  const float* hidden = (const float*)d_in[1];
  const float* w_qkv = (const float*)d_in[2];
  const float* w_o = (const float*)d_in[3];
  float* out = (float*)d_out;

  // workspace layout (bf16): total ~153 MB
  bf16_t* qkv = (bf16_t*)d_ws;                          // [2048, 8192]  33.6MB
  bf16_t* attn = qkv + (size_t)T_SEQ * QKV_N;           // [2048, 4096]  16.8MB
  bf16_t* hid_bf = attn + (size_t)T_SEQ * ATT_N;        // [2048, 3584]  14.7MB
  bf16_t* wqkv_t = hid_bf + (size_t)T_SEQ * HID_DIM;    // [8192, 3584]  58.7MB
  bf16_t* wo_t = wqkv_t + (size_t)QKV_N * HID_DIM;      // [3584, 4096]  29.4MB
  bf16_t* vtb = qkv + V_OFF;  // V^T lives in the V slot: vt(d,t)=vtb[d*8192+t]

  // 0) prep: bf16 convert + weight transposes
  convert_bf16<<<(T_SEQ * HID_DIM) / 2048, 256, 0, stream>>>(hidden, hid_bf);
  transpose_bf16<<<dim3(HID_DIM / 64, QKV_N / 64), 256, 0, stream>>>(
      w_qkv, wqkv_t, HID_DIM, QKV_N);
  transpose_bf16<<<dim3(ATT_N / 64, HID_DIM / 64), 256, 0, stream>>>(
      w_o, wo_t, ATT_N, HID_DIM);

  // 1) qkv = hidden @ w_qkv ; V columns routed transposed into vtb
  gemm_bt<bf16_t><<<dim3(QKV_N / 128, T_SEQ / 128), 256, 0, stream>>>(
      hid_bf, wqkv_t, qkv, vtb, V_OFF, T_SEQ, QKV_N, HID_DIM);
  // 2) rope on q,k in-place (V slot untouched)
  rope_kernel<<<dim3(NH + NKV, T_SEQ), 128, 0, stream>>>(positions, qkv);
  // 3) flash-decoding MFMA attention (2048 blocks, 4-way K split per block)
  attn_mfma<<<2048, 256, 0, stream>>>(qkv, vtb, attn);
  // 4) out = attn @ w_o
  gemm_bt<float><<<dim3(HID_DIM / 128, T_SEQ / 128), 256, 0, stream>>>(
      attn, wo_t, out, attn /*unused*/, 1 << 30, T_SEQ, HID_DIM, ATT_N);
}

// Round 7
// 838.762 us; speedup vs baseline: 1.2828x; 1.0056x over previous
//
#include <hip/hip_runtime.h>
#include <hip/hip_bf16.h>

// ---------------------------------------------------------------------------
// Gemma2 attention layer: qkv proj -> rope -> causal GQA attn (softcap) -> o proj
// T=2048 HID=3584 NH=16 NKV=8 HD=256
// R12 (= R11 hardened resubmit; previous round was an infra failure).
// Fixed-max softmax: soft-cap bounds scores to (-50,50), so the online max is
// pinned at 50: p = exp(tz-50) -- no max reduce, no rescale, no alpha.
// Row-sum l via ONE extra MFMA with a ones B-fragment (lacc) -> zero
// cross-lane shuffles in the main loop. V-frags hoisted before softmax
// (reuse kf's dead regs); __launch_bounds__(256,1) lets the allocator keep
// kf+vf live so loads batch instead of serializing (R10: ~9k stall cyc/tile).
// GEMMs (m97 structure) and prep unchanged.
// ---------------------------------------------------------------------------

#define T_SEQ 2048
#define HID_DIM 3584
#define NH 16
#define NKV 8
#define HD 256
#define QKV_N ((NH + 2 * NKV) * HD)   // 8192
#define ATT_N (NH * HD)               // 4096
#define V_OFF ((NH + NKV) * HD)       // 6144

typedef __bf16 bf16_t;
typedef bf16_t bf16x8 __attribute__((ext_vector_type(8)));
typedef float f32x4 __attribute__((ext_vector_type(4)));

// async global->LDS, 16B per lane; LDS dest is wave-uniform base + lane*16
__device__ __forceinline__ void gload16(const bf16_t* g, bf16_t* l) {
  __builtin_amdgcn_global_load_lds(
      (const __attribute__((address_space(1))) unsigned int*)g,
      (__attribute__((address_space(3))) unsigned int*)l, 16, 0, 0);
}

// ---------------------------------------------------------------------------
// Prep 1: fp32 -> bf16 linear convert (hidden_states). n = grid*256*8 exactly.
// ---------------------------------------------------------------------------
__global__ __launch_bounds__(256) void convert_bf16(
    const float* __restrict__ in, bf16_t* __restrict__ out) {
  const long i = ((long)blockIdx.x * 256 + threadIdx.x) * 8;
  const float4 f0 = *(const float4*)(in + i);
  const float4 f1 = *(const float4*)(in + i + 4);
  bf16x8 v;
  v[0] = (bf16_t)f0.x; v[1] = (bf16_t)f0.y; v[2] = (bf16_t)f0.z; v[3] = (bf16_t)f0.w;
  v[4] = (bf16_t)f1.x; v[5] = (bf16_t)f1.y; v[6] = (bf16_t)f1.z; v[7] = (bf16_t)f1.w;
  *(bf16x8*)(out + i) = v;
}

// ---------------------------------------------------------------------------
// Prep 2: transpose + convert: in [K,N] fp32 -> out [N,K] bf16. 64x64 tiles,
// coalesced reads (float4) and writes (bf16x8) via LDS.
// ---------------------------------------------------------------------------
__global__ __launch_bounds__(256) void transpose_bf16(
    const float* __restrict__ in, bf16_t* __restrict__ out, int K, int N) {
  __shared__ __align__(16) bf16_t tile[64][80];  // [n][k], 160B rows (16B-aligned)
  const int k0 = blockIdx.x * 64;
  const int n0 = blockIdx.y * 64;
  const int t = threadIdx.x;
  const int rr = t >> 4;          // 0..15 (k within pass)
  const int rc = (t & 15) * 4;    // n offset
#pragma unroll
  for (int i = 0; i < 4; ++i) {
    const int k = rr + i * 16;
    const float4 v = *(const float4*)(in + (long)(k0 + k) * N + n0 + rc);
    tile[rc + 0][k] = (bf16_t)v.x;
    tile[rc + 1][k] = (bf16_t)v.y;
    tile[rc + 2][k] = (bf16_t)v.z;
    tile[rc + 3][k] = (bf16_t)v.w;
  }
  __syncthreads();
  const int wn = t >> 3;          // 0..31
  const int wk = (t & 7) * 8;     // 0..56
#pragma unroll
  for (int i = 0; i < 2; ++i) {
    const int n = wn + i * 32;
    *(bf16x8*)(out + (long)(n0 + n) * K + k0 + wk) = *(const bf16x8*)&tile[n][wk];
  }
}

// ---------------------------------------------------------------------------
// GEMM (m97 structure): C[M,N] = A[M,K] @ Bt[N,K]^T, both bf16 row-major.
// Block 256 (4 waves), tile 128x128, BK=32. Columns >= voff are written
// TRANSPOSED to Vt[(col-voff)*QKV_N + row].
// ---------------------------------------------------------------------------
template <typename TC>
__global__ __launch_bounds__(256) void gemm_bt(
    const bf16_t* __restrict__ A, const bf16_t* __restrict__ Bt,
    TC* __restrict__ C, bf16_t* __restrict__ Vt, int voff,
    int M, int N, int K) {
  const int n0 = blockIdx.x * 128;
  const int m0 = blockIdx.y * 128;
  const int t = threadIdx.x;
  const int w = t >> 6;
  const int lane = t & 63;
  const int l16 = lane & 15;
  const int quad = lane >> 4;

  __shared__ __align__(16) bf16_t As[128][32];  // 8KB
  __shared__ __align__(16) bf16_t Bs[128][32];  // 8KB

  f32x4 acc[4][4];
#pragma unroll
  for (int i = 0; i < 4; ++i)
#pragma unroll
    for (int j = 0; j < 4; ++j) acc[i][j] = f32x4{0, 0, 0, 0};

  const int srow = lane >> 2;        // row within 16-row unit
  const int scol = (lane & 3) * 8;   // elem col within BK=32
  const bf16_t* gsrc;
  bf16_t* lbase;
  if (w < 2) {
    gsrc = A + (long)(m0 + w * 64 + srow) * K + scol;
    lbase = &As[w * 64][0];
  } else {
    gsrc = Bt + (long)(n0 + (w - 2) * 64 + srow) * K + scol;
    lbase = &Bs[(w - 2) * 64][0];
  }

  const int wm = w & 1;
  const int wn = w >> 1;

  for (int k0 = 0; k0 < K; k0 += 32) {
#pragma unroll
    for (int j = 0; j < 4; ++j)
      gload16(gsrc + (long)j * 16 * K + k0, lbase + j * (16 * 32));
    __syncthreads();

    bf16x8 af[4], bfr[4];
#pragma unroll
    for (int i = 0; i < 4; ++i) {
      af[i] = *(const bf16x8*)&As[wm * 64 + i * 16 + l16][quad * 8];
      bfr[i] = *(const bf16x8*)&Bs[wn * 64 + i * 16 + l16][quad * 8];
    }
#pragma unroll
    for (int i = 0; i < 4; ++i)
#pragma unroll
      for (int j = 0; j < 4; ++j)
        acc[i][j] = __builtin_amdgcn_mfma_f32_16x16x32_bf16(af[i], bfr[j],
                                                            acc[i][j], 0, 0, 0);
    __syncthreads();
  }

#pragma unroll
  for (int i = 0; i < 4; ++i) {
    const int row = m0 + wm * 64 + i * 16 + quad * 4;
#pragma unroll
    for (int j = 0; j < 4; ++j) {
      const int col = n0 + wn * 64 + j * 16 + l16;
#pragma unroll
      for (int r = 0; r < 4; ++r) {
        if (col >= voff)
          Vt[(long)(col - voff) * QKV_N + (row + r)] = (bf16_t)acc[i][j][r];
        else
          C[(long)(row + r) * N + col] = (TC)acc[i][j][r];
      }
    }
  }
}

// ---------------------------------------------------------------------------
// Neox-style RoPE over full HD=256, in-place on bf16 qkv (q: 16 heads, k: 8).
// ---------------------------------------------------------------------------
__global__ void rope_kernel(const int* __restrict__ positions,
                            bf16_t* __restrict__ qkv) {
  const int head = blockIdx.x;   // 0..23 : 0..15 q heads, 16..23 k heads
  const int trow = blockIdx.y;
  const int d = threadIdx.x;     // 0..127 (pairs with d+128)
  const long col0 = (head < NH) ? (long)head * HD
                                : (long)(NH * HD) + (long)(head - NH) * HD;
  bf16_t* p = qkv + (long)trow * QKV_N + col0;
  const float pos = (float)positions[trow];
  const float inv_freq = exp2f(-(float)d * (13.287712379549449f / 128.0f));
  const float ang = pos * inv_freq;
  float s, c;
  sincosf(ang, &s, &c);
  const float x1 = (float)p[d];
  const float x2 = (float)p[d + 128];
  p[d]       = (bf16_t)(x1 * c - x2 * s);
  p[d + 128] = (bf16_t)(x2 * c + x1 * s);
}

// ---------------------------------------------------------------------------
// R12 flash attention: one block per (head, 16-row q-chunk); 4 waves split the
// key-tile range (flash-decoding); fixed-max softmax (m=50, soft-cap bound):
//   p = exp2(C2 * rcp(exp2(sacc*C1) + 1))  [== exp(50*tanh(s/50) - 50)]
// Row-sums via a ones-B MFMA (lacc); NO cross-lane ops in the loop.
// Combine: plain sums (no exp weighting). kvh pinned to XCD (lid&7).
// __launch_bounds__(256,1): allow the allocator to keep kf+vf batched.
// ---------------------------------------------------------------------------
__global__ __launch_bounds__(256, 1) void attn_mfma(
    const bf16_t* __restrict__ qkv, const bf16_t* __restrict__ vt,
    bf16_t* __restrict__ out /* [T, 4096] */) {
  const int lid = blockIdx.x;            // 0..2047
  const int kvh = lid & 7;               // XCD-pinned KV head
  const int slot = lid >> 3;             // 0..255
  const int h = 2 * kvh + (slot & 1);
  const int chunk = 127 - (slot >> 1);   // heavy chunks dispatched first
  const int q0 = chunk * 16;
  const int ktiles = (chunk >> 1) + 1;   // 32-key tiles covering keys<=q0+15
  const int t = threadIdx.x;
  const int w = t >> 6;
  const int lane = t & 63;
  const int l16 = lane & 15;
  const int quad = lane >> 4;
  // 4-way key split across waves
  const int base = ktiles >> 2;
  const int rem = ktiles & 3;
  const int cnt = base + (w < rem ? 1 : 0);
  const int start = w * base + (w < rem ? w : rem);

  __shared__ __align__(16) bf16_t Ps[4][16][40];  // per-wave P slab (5KB)
  __shared__ float sl[4][16];
  __shared__ __align__(16) float slabA[16][260];  // padded: 2-way banks only
  __shared__ __align__(16) float slabB[16][260];

  // softcap+exp constants (exp2 domain):
  // e = exp2(sacc*C1) == exp(2*score/50);  p = exp2(C2/(e+1)) == exp(tz-50)
  const float C1 = 0.0036067376022224085f;   // SCALE*(2/50)*log2(e)
  const float C2 = -144.26950408889634f;     // -100*log2(e)

  // Q A-frags: A[m=l16][k=quad*8+j], d in 8 steps of 32 (same rows all waves)
  bf16x8 qf[8];
  const bf16_t* qbase = qkv + (long)(q0 + l16) * QKV_N + h * HD + quad * 8;
#pragma unroll
  for (int s = 0; s < 8; ++s) qf[s] = *(const bf16x8*)(qbase + s * 32);

  const bf16_t* kbase = qkv + (long)l16 * QKV_N + (NH * HD) + kvh * HD + quad * 8;
  const bf16_t* vbase = vt + (long)(kvh * HD + l16) * QKV_N + quad * 8;

  bf16x8 onesf;
#pragma unroll
  for (int j = 0; j < 8; ++j) onesf[j] = (bf16_t)1.0f;

  f32x4 oacc[16];  // O[16q][256d]: frag nt -> cols nt*16+l16
#pragma unroll
  for (int nt = 0; nt < 16; ++nt) oacc[nt] = f32x4{0, 0, 0, 0};
  f32x4 lacc = f32x4{0, 0, 0, 0};  // row-sums via ones-MFMA

  for (int kt = start; kt < start + cnt; ++kt) {
    // K B-frags: B[n=key16][k=d], 2 key-groups x 8 d-steps
    bf16x8 kf[2][8];
    const bf16_t* kp = kbase + (long)(kt * 32) * QKV_N;
#pragma unroll
    for (int g = 0; g < 2; ++g)
#pragma unroll
      for (int s = 0; s < 8; ++s)
        kf[g][s] = *(const bf16x8*)(kp + (long)(g * 16) * QKV_N + s * 32);

    f32x4 sacc[2] = {f32x4{0, 0, 0, 0}, f32x4{0, 0, 0, 0}};
    __builtin_amdgcn_s_setprio(1);
#pragma unroll
    for (int g = 0; g < 2; ++g)
#pragma unroll
      for (int s = 0; s < 8; ++s)
        sacc[g] = __builtin_amdgcn_mfma_f32_16x16x32_bf16(qf[s], kf[g][s],
                                                          sacc[g], 0, 0, 0);
    __builtin_amdgcn_s_setprio(0);

    // V^T B-frags for PV, hoisted before softmax (kf is dead: regs reuse)
    bf16x8 vf[16];
    {
      const bf16_t* vp = vbase + kt * 32;
#pragma unroll
      for (int nt = 0; nt < 16; ++nt)
        vf[nt] = *(const bf16x8*)(vp + (long)(nt * 16) * QKV_N);
    }

    // fixed-max softmax: p = exp(tz - 50); masked -> 0. No reductions.
#pragma unroll
    for (int r = 0; r < 4; ++r) {
      const int row = q0 + quad * 4 + r;
#pragma unroll
      for (int g = 0; g < 2; ++g) {
        const float e2 = exp2f(sacc[g][r] * C1);
        float p = exp2f(C2 * __builtin_amdgcn_rcpf(e2 + 1.0f));
        const int col = kt * 32 + g * 16 + l16;
        p = (col <= row) ? p : 0.0f;
        Ps[w][quad * 4 + r][g * 16 + l16] = (bf16_t)p;
      }
    }

    // wave-internal transpose: C-layout write above, A-layout read here
    const bf16x8 pa = *(const bf16x8*)&Ps[w][l16][quad * 8];

    __builtin_amdgcn_s_setprio(1);
    // row-sum via ones-MFMA: every lane gets its rows' l in lacc[r]
    lacc = __builtin_amdgcn_mfma_f32_16x16x32_bf16(pa, onesf, lacc, 0, 0, 0);
    // PV: 16 independent accumulator chains
#pragma unroll
    for (int nt = 0; nt < 16; ++nt)
      oacc[nt] = __builtin_amdgcn_mfma_f32_16x16x32_bf16(pa, vf[nt],
                                                         oacc[nt], 0, 0, 0);
    __builtin_amdgcn_s_setprio(0);
  }

  // ---- once-per-block combine of the 4 wave partials (plain sums) ----------
  if (l16 == 0) {
#pragma unroll
    for (int r = 0; r < 4; ++r) sl[w][quad * 4 + r] = lacc[r];
  }
  __syncthreads();

  float lsum[4];
#pragma unroll
  for (int r = 0; r < 4; ++r) {
    const int row = quad * 4 + r;
    lsum[r] = (sl[0][row] + sl[1][row]) + (sl[2][row] + sl[3][row]);
  }

  // tree reduce: (1 -> A, 3 -> B) ; (0 += A, 2 += B) ; (2 -> A) ; (0 += A)
  if (w == 1 || w == 3) {
    float(*slab)[260] = (w == 1) ? slabA : slabB;
#pragma unroll
    for (int r = 0; r < 4; ++r)
#pragma unroll
      for (int nt = 0; nt < 16; ++nt)
        slab[quad * 4 + r][nt * 16 + l16] = oacc[nt][r];
  }
  __syncthreads();
  if (w == 0) {
#pragma unroll
    for (int r = 0; r < 4; ++r)
#pragma unroll
      for (int nt = 0; nt < 16; ++nt)
        oacc[nt][r] += slabA[quad * 4 + r][nt * 16 + l16];
  } else if (w == 2) {
#pragma unroll
    for (int r = 0; r < 4; ++r)
#pragma unroll
      for (int nt = 0; nt < 16; ++nt)
        oacc[nt][r] += slabB[quad * 4 + r][nt * 16 + l16];
  }
  __syncthreads();
  if (w == 2) {
#pragma unroll
    for (int r = 0; r < 4; ++r)
#pragma unroll
      for (int nt = 0; nt < 16; ++nt)
        slabA[quad * 4 + r][nt * 16 + l16] = oacc[nt][r];
  }
  __syncthreads();
  if (w == 0) {
#pragma unroll
    for (int r = 0; r < 4; ++r) {
      const float inv = 1.0f / lsum[r];
      bf16_t* op = out + (long)(q0 + quad * 4 + r) * ATT_N + h * HD + l16;
#pragma unroll
      for (int nt = 0; nt < 16; ++nt)
        op[nt * 16] =
            (bf16_t)((oacc[nt][r] + slabA[quad * 4 + r][nt * 16 + l16]) * inv);
    }
  }
}

// ---------------------------------------------------------------------------
extern "C" void kernel_launch(void* const* d_in, const int* in_sizes, int n_in,
                              void* d_out, int out_size, void* d_ws, size_t ws_size,
                              hipStream_t stream) {
  const int* positions = (const int*)d_in[0];
  const float* hidden = (const float*)d_in[1];
  const float* w_qkv = (const float*)d_in[2];
  const float* w_o = (const float*)d_in[3];
  float* out = (float*)d_out;

  // workspace layout (bf16): total ~153 MB
  bf16_t* qkv = (bf16_t*)d_ws;                          // [2048, 8192]  33.6MB
  bf16_t* attn = qkv + (size_t)T_SEQ * QKV_N;           // [2048, 4096]  16.8MB
  bf16_t* hid_bf = attn + (size_t)T_SEQ * ATT_N;        // [2048, 3584]  14.7MB
  bf16_t* wqkv_t = hid_bf + (size_t)T_SEQ * HID_DIM;    // [8192, 3584]  58.7MB
  bf16_t* wo_t = wqkv_t + (size_t)QKV_N * HID_DIM;      // [3584, 4096]  29.4MB
  bf16_t* vtb = qkv + V_OFF;  // V^T lives in the V slot: vt(d,t)=vtb[d*8192+t]

  // 0) prep: bf16 convert + weight transposes
  convert_bf16<<<(T_SEQ * HID_DIM) / 2048, 256, 0, stream>>>(hidden, hid_bf);
  transpose_bf16<<<dim3(HID_DIM / 64, QKV_N / 64), 256, 0, stream>>>(
      w_qkv, wqkv_t, HID_DIM, QKV_N);
  transpose_bf16<<<dim3(ATT_N / 64, HID_DIM / 64), 256, 0, stream>>>(
      w_o, wo_t, ATT_N, HID_DIM);

  // 1) qkv = hidden @ w_qkv ; V columns routed transposed into vtb
  gemm_bt<bf16_t><<<dim3(QKV_N / 128, T_SEQ / 128), 256, 0, stream>>>(
      hid_bf, wqkv_t, qkv, vtb, V_OFF, T_SEQ, QKV_N, HID_DIM);
  // 2) rope on q,k in-place (V slot untouched)
  rope_kernel<<<dim3(NH + NKV, T_SEQ), 128, 0, stream>>>(positions, qkv);
  // 3) flash-decoding MFMA attention (2048 blocks, 4-way K split per block)
  attn_mfma<<<2048, 256, 0, stream>>>(qkv, vtb, attn);
  // 4) out = attn @ w_o
  gemm_bt<float><<<dim3(HID_DIM / 128, T_SEQ / 128), 256, 0, stream>>>(
      attn, wo_t, out, attn /*unused*/, 1 << 30, T_SEQ, HID_DIM, ATT_N);
}

// Round 8
// 691.307 us; speedup vs baseline: 1.5565x; 1.2133x over previous
//
#include <hip/hip_runtime.h>
#include <hip/hip_bf16.h>

// ---------------------------------------------------------------------------
// Gemma2 attention layer: qkv proj -> rope -> causal GQA attn (softcap) -> o proj
// T=2048 HID=3584 NH=16 NKV=8 HD=256
// R13: block-cooperative LDS-staged attention. R12 was serial-L2-latency bound
// (~5.5k stall cyc/tile/wave on scattered K/V b128 loads, concurrency ~1.7).
// New structure: block = (head, 64 q-rows), 4 waves x 16 rows; per 32-key tile
// the block cooperatively stages K (32x256) + V^T (256x32) into double-buffered
// LDS via global_load_lds (async, issued for kt+1 before computing kt; ONE
// barrier per tile = T3 minimum 2-phase). T2 XOR-swizzle applied via
// pre-swizzled GLOBAL source (gload_lds writes linearly) + swizzled LDS reads.
// All waves see all keys -> no cross-wave combine. Fixed-max softmax +
// ones-MFMA row-sum kept from R12 (verified numerics).
// GEMMs (m97 structure) and prep unchanged.
// ---------------------------------------------------------------------------

#define T_SEQ 2048
#define HID_DIM 3584
#define NH 16
#define NKV 8
#define HD 256
#define QKV_N ((NH + 2 * NKV) * HD)   // 8192
#define ATT_N (NH * HD)               // 4096
#define V_OFF ((NH + NKV) * HD)       // 6144

typedef __bf16 bf16_t;
typedef bf16_t bf16x8 __attribute__((ext_vector_type(8)));
typedef float f32x4 __attribute__((ext_vector_type(4)));

// async global->LDS, 16B per lane; LDS dest is wave-uniform base + lane*16
__device__ __forceinline__ void gload16(const bf16_t* g, bf16_t* l) {
  __builtin_amdgcn_global_load_lds(
      (const __attribute__((address_space(1))) unsigned int*)g,
      (__attribute__((address_space(3))) unsigned int*)l, 16, 0, 0);
}

// ---------------------------------------------------------------------------
// Prep 1: fp32 -> bf16 linear convert (hidden_states). n = grid*256*8 exactly.
// ---------------------------------------------------------------------------
__global__ __launch_bounds__(256) void convert_bf16(
    const float* __restrict__ in, bf16_t* __restrict__ out) {
  const long i = ((long)blockIdx.x * 256 + threadIdx.x) * 8;
  const float4 f0 = *(const float4*)(in + i);
  const float4 f1 = *(const float4*)(in + i + 4);
  bf16x8 v;
  v[0] = (bf16_t)f0.x; v[1] = (bf16_t)f0.y; v[2] = (bf16_t)f0.z; v[3] = (bf16_t)f0.w;
  v[4] = (bf16_t)f1.x; v[5] = (bf16_t)f1.y; v[6] = (bf16_t)f1.z; v[7] = (bf16_t)f1.w;
  *(bf16x8*)(out + i) = v;
}

// ---------------------------------------------------------------------------
// Prep 2: transpose + convert: in [K,N] fp32 -> out [N,K] bf16. 64x64 tiles,
// coalesced reads (float4) and writes (bf16x8) via LDS.
// ---------------------------------------------------------------------------
__global__ __launch_bounds__(256) void transpose_bf16(
    const float* __restrict__ in, bf16_t* __restrict__ out, int K, int N) {
  __shared__ __align__(16) bf16_t tile[64][80];  // [n][k], 160B rows (16B-aligned)
  const int k0 = blockIdx.x * 64;
  const int n0 = blockIdx.y * 64;
  const int t = threadIdx.x;
  const int rr = t >> 4;          // 0..15 (k within pass)
  const int rc = (t & 15) * 4;    // n offset
#pragma unroll
  for (int i = 0; i < 4; ++i) {
    const int k = rr + i * 16;
    const float4 v = *(const float4*)(in + (long)(k0 + k) * N + n0 + rc);
    tile[rc + 0][k] = (bf16_t)v.x;
    tile[rc + 1][k] = (bf16_t)v.y;
    tile[rc + 2][k] = (bf16_t)v.z;
    tile[rc + 3][k] = (bf16_t)v.w;
  }
  __syncthreads();
  const int wn = t >> 3;          // 0..31
  const int wk = (t & 7) * 8;     // 0..56
#pragma unroll
  for (int i = 0; i < 2; ++i) {
    const int n = wn + i * 32;
    *(bf16x8*)(out + (long)(n0 + n) * K + k0 + wk) = *(const bf16x8*)&tile[n][wk];
  }
}

// ---------------------------------------------------------------------------
// GEMM (m97 structure): C[M,N] = A[M,K] @ Bt[N,K]^T, both bf16 row-major.
// Block 256 (4 waves), tile 128x128, BK=32. Columns >= voff are written
// TRANSPOSED to Vt[(col-voff)*QKV_N + row].
// ---------------------------------------------------------------------------
template <typename TC>
__global__ __launch_bounds__(256) void gemm_bt(
    const bf16_t* __restrict__ A, const bf16_t* __restrict__ Bt,
    TC* __restrict__ C, bf16_t* __restrict__ Vt, int voff,
    int M, int N, int K) {
  const int n0 = blockIdx.x * 128;
  const int m0 = blockIdx.y * 128;
  const int t = threadIdx.x;
  const int w = t >> 6;
  const int lane = t & 63;
  const int l16 = lane & 15;
  const int quad = lane >> 4;

  __shared__ __align__(16) bf16_t As[128][32];  // 8KB
  __shared__ __align__(16) bf16_t Bs[128][32];  // 8KB

  f32x4 acc[4][4];
#pragma unroll
  for (int i = 0; i < 4; ++i)
#pragma unroll
    for (int j = 0; j < 4; ++j) acc[i][j] = f32x4{0, 0, 0, 0};

  const int srow = lane >> 2;        // row within 16-row unit
  const int scol = (lane & 3) * 8;   // elem col within BK=32
  const bf16_t* gsrc;
  bf16_t* lbase;
  if (w < 2) {
    gsrc = A + (long)(m0 + w * 64 + srow) * K + scol;
    lbase = &As[w * 64][0];
  } else {
    gsrc = Bt + (long)(n0 + (w - 2) * 64 + srow) * K + scol;
    lbase = &Bs[(w - 2) * 64][0];
  }

  const int wm = w & 1;
  const int wn = w >> 1;

  for (int k0 = 0; k0 < K; k0 += 32) {
#pragma unroll
    for (int j = 0; j < 4; ++j)
      gload16(gsrc + (long)j * 16 * K + k0, lbase + j * (16 * 32));
    __syncthreads();

    bf16x8 af[4], bfr[4];
#pragma unroll
    for (int i = 0; i < 4; ++i) {
      af[i] = *(const bf16x8*)&As[wm * 64 + i * 16 + l16][quad * 8];
      bfr[i] = *(const bf16x8*)&Bs[wn * 64 + i * 16 + l16][quad * 8];
    }
#pragma unroll
    for (int i = 0; i < 4; ++i)
#pragma unroll
      for (int j = 0; j < 4; ++j)
        acc[i][j] = __builtin_amdgcn_mfma_f32_16x16x32_bf16(af[i], bfr[j],
                                                            acc[i][j], 0, 0, 0);
    __syncthreads();
  }

#pragma unroll
  for (int i = 0; i < 4; ++i) {
    const int row = m0 + wm * 64 + i * 16 + quad * 4;
#pragma unroll
    for (int j = 0; j < 4; ++j) {
      const int col = n0 + wn * 64 + j * 16 + l16;
#pragma unroll
      for (int r = 0; r < 4; ++r) {
        if (col >= voff)
          Vt[(long)(col - voff) * QKV_N + (row + r)] = (bf16_t)acc[i][j][r];
        else
          C[(long)(row + r) * N + col] = (TC)acc[i][j][r];
      }
    }
  }
}

// ---------------------------------------------------------------------------
// Neox-style RoPE over full HD=256, in-place on bf16 qkv (q: 16 heads, k: 8).
// ---------------------------------------------------------------------------
__global__ void rope_kernel(const int* __restrict__ positions,
                            bf16_t* __restrict__ qkv) {
  const int head = blockIdx.x;   // 0..23 : 0..15 q heads, 16..23 k heads
  const int trow = blockIdx.y;
  const int d = threadIdx.x;     // 0..127 (pairs with d+128)
  const long col0 = (head < NH) ? (long)head * HD
                                : (long)(NH * HD) + (long)(head - NH) * HD;
  bf16_t* p = qkv + (long)trow * QKV_N + col0;
  const float pos = (float)positions[trow];
  const float inv_freq = exp2f(-(float)d * (13.287712379549449f / 128.0f));
  const float ang = pos * inv_freq;
  float s, c;
  sincosf(ang, &s, &c);
  const float x1 = (float)p[d];
  const float x2 = (float)p[d + 128];
  p[d]       = (bf16_t)(x1 * c - x2 * s);
  p[d + 128] = (bf16_t)(x2 * c + x1 * s);
}

// ---------------------------------------------------------------------------
// R13 flash attention: block-cooperative, LDS-staged, double-buffered.
// Block = (head, 64 q-rows); wave w owns rows q0+16w..+15, iterates ALL key
// tiles (causal-masked). Per tile: issue async stage of kt+1 into buf^1 ->
// compute from buf (kf/vf LDS reads, swizzled) -> one __syncthreads.
// K LDS tile [32 key][256 d], 16B-unit swizzle u^=(row&7);
// V LDS tile [256 d][32 key], u^=(row&3). Source pre-swizzled (rule #21).
// Fixed-max softmax (m=50) + ones-MFMA row-sum; no cross-wave combine.
// ---------------------------------------------------------------------------
__global__ __launch_bounds__(256) void attn_mfma(
    const bf16_t* __restrict__ qkv, const bf16_t* __restrict__ vt,
    bf16_t* __restrict__ out /* [T, 4096] */) {
  const int lid = blockIdx.x;            // 0..511
  const int kvh = lid & 7;               // XCD-pinned KV head
  const int h = 2 * kvh + ((lid >> 3) & 1);
  const int slot = lid >> 4;             // 0..31
  const int chunk = 31 - slot;           // heavy (long) blocks first
  const int q0 = chunk * 64;
  const int ktiles = 2 * chunk + 2;      // 32-key tiles covering keys<=q0+63
  const int t = threadIdx.x;
  const int w = t >> 6;
  const int lane = t & 63;
  const int l16 = lane & 15;
  const int quad = lane >> 4;

  __shared__ __align__(16) bf16_t Ks[2][32 * 256];   // 2 x 16KB [key][d]
  __shared__ __align__(16) bf16_t Vs[2][256 * 32];   // 2 x 16KB [d][key]
  __shared__ __align__(16) bf16_t Ps[4][16][40];     // per-wave P slab (5KB)

  // softcap+exp constants (exp2 domain):
  // e = exp2(sacc*C1) == exp(2*score/50);  p = exp2(C2/(e+1)) == exp(tz-50)
  const float C1 = 0.0036067376022224085f;   // SCALE*(2/50)*log2(e)
  const float C2 = -144.26950408889634f;     // -100*log2(e)

  // Q A-frags: rows q0+16w+l16, d in 8 steps of 32
  bf16x8 qf[8];
  const bf16_t* qbase =
      qkv + (long)(q0 + w * 16 + l16) * QKV_N + h * HD + quad * 8;
#pragma unroll
  for (int s = 0; s < 8; ++s) qf[s] = *(const bf16x8*)(qbase + s * 32);

  bf16x8 onesf;
#pragma unroll
  for (int j = 0; j < 8; ++j) onesf[j] = (bf16_t)1.0f;

  f32x4 oacc[16];  // O[16q][256d]: frag nt -> cols nt*16+l16
#pragma unroll
  for (int nt = 0; nt < 16; ++nt) oacc[nt] = f32x4{0, 0, 0, 0};
  f32x4 lacc = f32x4{0, 0, 0, 0};  // row-sums via ones-MFMA

  const bf16_t* kglob = qkv + (long)(NH * HD) + kvh * HD;  // + row*QKV_N + d
  const bf16_t* vglob = vt + (long)(kvh * HD) * QKV_N;     // + d*QKV_N + key

  // cooperative stage of key-tile kt_ into buffer b (async; rule #21 swizzle)
  auto STAGE = [&](int kt_, int b) {
#pragma unroll
    for (int j = 0; j < 4; ++j) {   // K: 1024 16B-units, 32/row, u^=(row&7)
      const int U = j * 256 + w * 64 + lane;
      const int row = U >> 5, u = U & 31;
      gload16(kglob + (long)(kt_ * 32 + row) * QKV_N + ((u ^ (row & 7)) << 3),
              &Ks[b][(j * 256 + w * 64) * 8]);
    }
#pragma unroll
    for (int j = 0; j < 4; ++j) {   // V: 1024 16B-units, 4/row, u^=(row&3)
      const int U = j * 256 + w * 64 + lane;
      const int row = U >> 2, u = U & 3;
      gload16(vglob + (long)row * QKV_N + kt_ * 32 + ((u ^ (row & 3)) << 3),
              &Vs[b][(j * 256 + w * 64) * 8]);
    }
  };

  STAGE(0, 0);
  __syncthreads();

  int cur = 0;
  for (int kt = 0; kt < ktiles; ++kt) {
    if (kt + 1 < ktiles) STAGE(kt + 1, cur ^ 1);

    // K frags from LDS: kf[g][s] = K[key=g*16+l16][d=quad*8+s*32]
    f32x4 sacc[2] = {f32x4{0, 0, 0, 0}, f32x4{0, 0, 0, 0}};
    __builtin_amdgcn_s_setprio(1);
#pragma unroll
    for (int g = 0; g < 2; ++g) {
      const int krow = g * 16 + l16;
      const bf16_t* kr = &Ks[cur][krow * 256];
      const int sw = l16 & 7;
#pragma unroll
      for (int s = 0; s < 8; ++s) {
        const bf16x8 kf = *(const bf16x8*)(kr + (((quad + s * 4) ^ sw) << 3));
        sacc[g] = __builtin_amdgcn_mfma_f32_16x16x32_bf16(qf[s], kf,
                                                          sacc[g], 0, 0, 0);
      }
    }
    __builtin_amdgcn_s_setprio(0);

    // fixed-max softmax: p = exp(tz - 50); masked -> 0. No reductions.
#pragma unroll
    for (int r = 0; r < 4; ++r) {
      const int row = q0 + w * 16 + quad * 4 + r;
#pragma unroll
      for (int g = 0; g < 2; ++g) {
        const float e2 = exp2f(sacc[g][r] * C1);
        float p = exp2f(C2 * __builtin_amdgcn_rcpf(e2 + 1.0f));
        const int col = kt * 32 + g * 16 + l16;
        p = (col <= row) ? p : 0.0f;
        Ps[w][quad * 4 + r][g * 16 + l16] = (bf16_t)p;
      }
    }

    // wave-internal transpose: C-layout write above, A-layout read here
    const bf16x8 pa = *(const bf16x8*)&Ps[w][l16][quad * 8];

    __builtin_amdgcn_s_setprio(1);
    lacc = __builtin_amdgcn_mfma_f32_16x16x32_bf16(pa, onesf, lacc, 0, 0, 0);
    // V frags from LDS: vf[nt] = V^T[d=nt*16+l16][keys quad*8..+7]
    {
      const int sw = l16 & 3;
#pragma unroll
      for (int nt = 0; nt < 16; ++nt) {
        const bf16x8 vf =
            *(const bf16x8*)(&Vs[cur][(nt * 16 + l16) * 32] +
                             ((quad ^ sw) << 3));
        oacc[nt] = __builtin_amdgcn_mfma_f32_16x16x32_bf16(pa, vf,
                                                           oacc[nt], 0, 0, 0);
      }
    }
    __builtin_amdgcn_s_setprio(0);

    __syncthreads();  // staged kt+1 landed (vmcnt drain) + buf reads done
    cur ^= 1;
  }

  // epilogue: each wave owns complete rows; no combine
#pragma unroll
  for (int r = 0; r < 4; ++r) {
    const float inv = 1.0f / lacc[r];
    bf16_t* op =
        out + (long)(q0 + w * 16 + quad * 4 + r) * ATT_N + h * HD + l16;
#pragma unroll
    for (int nt = 0; nt < 16; ++nt) op[nt * 16] = (bf16_t)(oacc[nt][r] * inv);
  }
}

// ---------------------------------------------------------------------------
extern "C" void kernel_launch(void* const* d_in, const int* in_sizes, int n_in,
                              void* d_out, int out_size, void* d_ws, size_t ws_size,
                              hipStream_t stream) {
  const int* positions = (const int*)d_in[0];
  const float* hidden = (const float*)d_in[1];
  const float* w_qkv = (const float*)d_in[2];
  const float* w_o = (const float*)d_in[3];
  float* out = (float*)d_out;

  // workspace layout (bf16): total ~153 MB
  bf16_t* qkv = (bf16_t*)d_ws;                          // [2048, 8192]  33.6MB
  bf16_t* attn = qkv + (size_t)T_SEQ * QKV_N;           // [2048, 4096]  16.8MB
  bf16_t* hid_bf = attn + (size_t)T_SEQ * ATT_N;        // [2048, 3584]  14.7MB
  bf16_t* wqkv_t = hid_bf + (size_t)T_SEQ * HID_DIM;    // [8192, 3584]  58.7MB
  bf16_t* wo_t = wqkv_t + (size_t)QKV_N * HID_DIM;      // [3584, 4096]  29.4MB
  bf16_t* vtb = qkv + V_OFF;  // V^T lives in the V slot: vt(d,t)=vtb[d*8192+t]

  // 0) prep: bf16 convert + weight transposes
  convert_bf16<<<(T_SEQ * HID_DIM) / 2048, 256, 0, stream>>>(hidden, hid_bf);
  transpose_bf16<<<dim3(HID_DIM / 64, QKV_N / 64), 256, 0, stream>>>(
      w_qkv, wqkv_t, HID_DIM, QKV_N);
  transpose_bf16<<<dim3(ATT_N / 64, HID_DIM / 64), 256, 0, stream>>>(
      w_o, wo_t, ATT_N, HID_DIM);

  // 1) qkv = hidden @ w_qkv ; V columns routed transposed into vtb
  gemm_bt<bf16_t><<<dim3(QKV_N / 128, T_SEQ / 128), 256, 0, stream>>>(
      hid_bf, wqkv_t, qkv, vtb, V_OFF, T_SEQ, QKV_N, HID_DIM);
  // 2) rope on q,k in-place (V slot untouched)
  rope_kernel<<<dim3(NH + NKV, T_SEQ), 128, 0, stream>>>(positions, qkv);
  // 3) block-cooperative LDS-staged MFMA flash attention (512 blocks)
  attn_mfma<<<512, 256, 0, stream>>>(qkv, vtb, attn);
  // 4) out = attn @ w_o
  gemm_bt<float><<<dim3(HID_DIM / 128, T_SEQ / 128), 256, 0, stream>>>(
      attn, wo_t, out, attn /*unused*/, 1 << 30, T_SEQ, HID_DIM, ATT_N);
}